// Round 11
// baseline (1507.293 us; speedup 1.0000x reference)
//
#include <hip/hip_runtime.h>
#include <hip/hip_bf16.h>
#include <math.h>

typedef unsigned short u16;
typedef __bf16 bf16x8_t __attribute__((ext_vector_type(8)));
typedef float  f32x4_t  __attribute__((ext_vector_type(4)));
typedef float  f32x8_t  __attribute__((ext_vector_type(8)));
typedef u16    u16x4_t  __attribute__((ext_vector_type(4)));
typedef u16    u16x8_t  __attribute__((ext_vector_type(8)));

// ---------- helpers ----------
__device__ __forceinline__ u16 f2b(float f) {
  unsigned u = __builtin_bit_cast(unsigned, f);
  u += 0x7fffu + ((u >> 16) & 1u);      // RNE; inputs are finite
  return (u16)(u >> 16);
}
__device__ __forceinline__ float b2f(u16 h) {
  unsigned u = ((unsigned)h) << 16;
  return __builtin_bit_cast(float, u);
}
__device__ __forceinline__ float sigm_(float x) { return 1.0f / (1.0f + __expf(-x)); }
__device__ __forceinline__ float tanh_(float x) { return 1.0f - 2.0f / (__expf(2.0f * x) + 1.0f); }

__device__ __forceinline__ void gload16(const void* g, void* l) {
  __builtin_amdgcn_global_load_lds(
      (__attribute__((address_space(1))) void*)(g),
      (__attribute__((address_space(3))) void*)(l), 16, 0, 0);
}

// ==========================================================================
// Packed panel formats (k-plane = 8 consecutive k as 16B per row):
//  256-row tiles: [p 0..3][row 0..255][8 u16] = 8192 u16 (16 KB)
//  128-row tiles: [p 0..3][row 0..127][8 u16] = 4096 u16 ( 8 KB)
// Staging = contiguous 16B/thread wave loads; LDS image == packed tile ->
// conflict-free ds_read_b128 fragments.
// ==========================================================================

// ---------- fused activation pack: x|h|c -> A1p (KT=160; x 0..63, h 64..95, c 96..159) ----------
__global__ void pack_act_kernel(const float* __restrict__ x, const float* __restrict__ h,
                                const float* __restrict__ c, u16* __restrict__ A1p) {
  int mb = blockIdx.x, kt = blockIdx.y, t = threadIdx.x;
  const float* src; int C, ccol;
  if (kt < 64)      { src = x; C = 2048; ccol = kt * 32; }
  else if (kt < 96) { src = h; C = 1024; ccol = (kt - 64) * 32; }
  else              { src = c; C = 2048; ccol = (kt - 96) * 32; }
  const float* s = src + (long)(mb * 256 + t) * C + ccol;
  u16* d = A1p + ((long)(mb * 160 + kt)) * 8192 + t * 8;
#pragma unroll
  for (int p = 0; p < 4; ++p) {
    f32x8_t v = *(const f32x8_t*)(s + p * 8);
    u16x8_t o;
#pragma unroll
    for (int r = 0; r < 8; ++r) o[r] = f2b(v[r]);
    *(u16x8_t*)(d + p * 2048) = o;
  }
}

// ---------- fused W1 pack (transposed) -> W1tp[32nb][160kt][8192] ----------
__global__ void pack_w1_kernel(const float* __restrict__ w_if_x, const float* __restrict__ w_if_h,
                               const float* __restrict__ w_if_c, const float* __restrict__ w_c_x,
                               const float* __restrict__ w_c_h,  const float* __restrict__ w_o_x,
                               const float* __restrict__ w_o_h,  const float* __restrict__ w_r_x,
                               u16* __restrict__ W1tp) {
  int nb = blockIdx.x, kt = blockIdx.y, t = threadIdx.x;
  int n0g = nb * 256;
  const float* src; int N, nl, kl;
  if (n0g < 4096) {
    N = 4096; nl = n0g;
    if (kt < 64)      { src = w_if_x; kl = kt * 32; }
    else if (kt < 96) { src = w_if_h; kl = (kt - 64) * 32; }
    else              { src = w_if_c; kl = (kt - 96) * 32; }
  } else if (n0g < 6144) {
    N = 2048; nl = n0g - 4096;
    if (kt < 64)      { src = w_c_x; kl = kt * 32; }
    else if (kt < 96) { src = w_c_h; kl = (kt - 64) * 32; }
    else return;
  } else if (n0g < 7168) {
    N = 1024; nl = n0g - 6144;
    if (kt < 64)      { src = w_o_x; kl = kt * 32; }
    else if (kt < 96) { src = w_o_h; kl = (kt - 64) * 32; }
    else return;
  } else {
    N = 1024; nl = n0g - 7168;
    if (kt < 64)      { src = w_r_x; kl = kt * 32; }
    else return;
  }
  int n = nl + t;
  float tmp[32];
#pragma unroll
  for (int kk = 0; kk < 32; ++kk)
    tmp[kk] = src[(long)(kl + kk) * N + n];
  u16* d = W1tp + ((long)(nb * 160 + kt)) * 8192 + t * 8;
#pragma unroll
  for (int p = 0; p < 4; ++p) {
    u16x8_t o;
#pragma unroll
    for (int r = 0; r < 8; ++r) o[r] = f2b(tmp[p * 8 + r]);
    *(u16x8_t*)(d + p * 2048) = o;
  }
}

// ---------- W2 pack -> W2q[8cg][128kt][4096] (128-row tiles) ----------
__global__ void pack_w2_kernel(const float* __restrict__ w_o_c,
                               const float* __restrict__ w_r_proj, u16* __restrict__ W2q) {
  int cg = blockIdx.x, kt = blockIdx.y, t = threadIdx.x;   // block = 128 threads
  const float* src; int kl;
  if (kt < 64) { src = w_o_c;    kl = kt * 32; }
  else         { src = w_r_proj; kl = (kt - 64) * 32; }
  int n = cg * 128 + t;
  float tmp[32];
#pragma unroll
  for (int kk = 0; kk < 32; ++kk)
    tmp[kk] = src[(long)(kl + kk) * 1024 + n];
  u16* d = W2q + ((long)(cg * 128 + kt)) * 4096 + t * 8;
#pragma unroll
  for (int p = 0; p < 4; ++p) {
    u16x8_t o;
#pragma unroll
    for (int r = 0; r < 8; ++r) o[r] = f2b(tmp[p * 8 + r]);
    *(u16x8_t*)(d + p * 1024) = o;
  }
}

// ==========================================================================
// GEMM1: R4-exact 256x256 bf16, 16x16x32 MFMA, 8 waves (2M x 4N), BK=32,
// 3-slot LDS ring (96KB), stage t+2, boundary vmcnt(4), 1 barrier/tile.
// Structural floor ~985us established over R4-R9 (7 schedule variants).
// ==========================================================================
__global__ __launch_bounds__(512, 2) void gemm1_kernel(
    const u16* __restrict__ A, const u16* __restrict__ Bt, u16* __restrict__ Cout) {
  constexpr int KTF  = 160;
  constexpr int NCOL = 8192;
  constexpr int NBN  = 32;
  constexpr int SLOT = 16384;   // u16 per ring slot (A 8192 + B 8192)

  __shared__ u16 lds[3 * SLOT];  // 96 KiB

  int bid = blockIdx.x;
  int cpx = gridDim.x >> 3;
  bid = (bid & 7) * cpx + (bid >> 3);

  int mb = bid / NBN, nb = bid % NBN;
  int m0 = mb * 256, n0 = nb * 256;

  int NT = (nb < 16) ? 160 : ((nb < 28) ? 96 : 64);

  const int tid  = threadIdx.x;
  const int lane = tid & 63;
  const int wid  = tid >> 6;
  const int wr   = wid >> 2;       // 0..1
  const int wc   = wid & 3;        // 0..3
  const int hl16 = lane >> 4;      // 0..3 (k-plane)
  const int l15  = lane & 15;

  const int dstg = tid * 8;  // u16
  const u16* pA = A  + ((long)(mb * KTF)) * 8192 + dstg;
  const u16* pB = Bt + ((long)(nb * KTF)) * 8192 + dstg;

#define STAGE(t, s) do { \
    gload16(pA + (long)(t) * 8192,        &lds[(s) * SLOT + dstg]); \
    gload16(pA + (long)(t) * 8192 + 4096, &lds[(s) * SLOT + dstg + 4096]); \
    gload16(pB + (long)(t) * 8192,        &lds[(s) * SLOT + 8192 + dstg]); \
    gload16(pB + (long)(t) * 8192 + 4096, &lds[(s) * SLOT + 8192 + dstg + 4096]); } while (0)

  const int aoff = hl16 * 2048 + (wr * 128 + l15) * 8;  // + m*128 (16 rows)
  const int boff = hl16 * 2048 + (wc * 64  + l15) * 8;  // + n*128

  f32x4_t acc[8][4];
#pragma unroll
  for (int m = 0; m < 8; ++m)
#pragma unroll
    for (int n = 0; n < 4; ++n) acc[m][n] = (f32x4_t){0.f, 0.f, 0.f, 0.f};

  STAGE(0, 0); STAGE(1, 1);
  asm volatile("s_waitcnt vmcnt(4)" ::: "memory");
  __builtin_amdgcn_s_barrier();

  int slot = 0, s2 = 2;
  for (int t = 0; t < NT; ++t) {
    const u16* sA = &lds[slot * SLOT];
    const u16* sB = sA + 8192;
    const bool pre = (t + 2 < NT);
    if (pre) STAGE(t + 2, s2);

    bf16x8_t bv[4], av[8];
#pragma unroll
    for (int n = 0; n < 4; ++n) bv[n] = *(const bf16x8_t*)&sB[boff + n * 128];
#pragma unroll
    for (int m = 0; m < 8; ++m) av[m] = *(const bf16x8_t*)&sA[aoff + m * 128];

    __builtin_amdgcn_s_setprio(1);
#pragma unroll
    for (int m = 0; m < 8; ++m)
#pragma unroll
      for (int n = 0; n < 4; ++n)
        acc[m][n] = __builtin_amdgcn_mfma_f32_16x16x32_bf16(bv[n], av[m], acc[m][n], 0, 0, 0);
    __builtin_amdgcn_s_setprio(0);

    if (pre) asm volatile("s_waitcnt vmcnt(4)" ::: "memory");
    else     asm volatile("s_waitcnt vmcnt(0)" ::: "memory");
    __builtin_amdgcn_s_barrier();

    slot = (slot == 2) ? 0 : slot + 1;
    s2   = (s2   == 2) ? 0 : s2   + 1;
  }
#undef STAGE

  const int rowm = lane & 15;
  const int col4 = (lane >> 4) * 4;
#pragma unroll
  for (int m = 0; m < 8; ++m) {
    long rg = (long)(m0 + wr * 128 + m * 16 + rowm) * NCOL;
#pragma unroll
    for (int n = 0; n < 4; ++n) {
      int cg = n0 + wc * 64 + n * 16 + col4;
      u16x4_t o;
#pragma unroll
      for (int r = 0; r < 4; ++r) o[r] = f2b(acc[m][n][r]);
      *(u16x4_t*)&Cout[rg + cg] = o;
    }
  }
}

// ---------- pass2: gates -> c_new (fp32), A2 packed = [bf16(c_new) | bf16(tanh(c_new))] ----------
__global__ void pass2_kernel(const u16* __restrict__ G1, const float* __restrict__ c_t,
                             const float* __restrict__ bias_i, const float* __restrict__ bias_f,
                             const float* __restrict__ bias_c,
                             float* __restrict__ c_new_out, u16* __restrict__ A2p) {
  int mb = blockIdx.x, jg = blockIdx.y, t = threadIdx.x;
  int b = mb * 256 + t;
  int j0 = jg * 32;
  const u16* row = G1 + (long)b * 8192 + j0;
  const float* cp_p = c_t + (long)b * 2048 + j0;
  float* co_p = c_new_out + (long)b * 2048 + j0;
  u16* dc = A2p + ((long)(mb * 128 + jg)) * 8192 + t * 8;
  u16* dr = dc + (long)64 * 8192;

#pragma unroll
  for (int q = 0; q < 4; ++q) {
    u16x8_t ip = *(const u16x8_t*)(row + q * 8);
    u16x8_t fp = *(const u16x8_t*)(row + 2048 + q * 8);
    u16x8_t gp = *(const u16x8_t*)(row + 4096 + q * 8);
    f32x8_t cp = *(const f32x8_t*)(cp_p + q * 8);
    f32x8_t bi = *(const f32x8_t*)(bias_i + j0 + q * 8);
    f32x8_t bf = *(const f32x8_t*)(bias_f + j0 + q * 8);
    f32x8_t bc = *(const f32x8_t*)(bias_c + j0 + q * 8);
    f32x8_t cn;
    u16x8_t cb, rb;
#pragma unroll
    for (int r = 0; r < 8; ++r) {
      float ig = sigm_(b2f(ip[r]) + bi[r]);
      float fg = sigm_(b2f(fp[r]) + bf[r]);
      float g  = tanh_(b2f(gp[r]) + bc[r]);
      float c  = fg * cp[r] + ig * g;
      cn[r] = c;
      cb[r] = f2b(c);
      rb[r] = f2b(tanh_(c));
    }
    *(f32x8_t*)(co_p + q * 8) = cn;
    *(u16x8_t*)(dc + q * 2048) = cb;
    *(u16x8_t*)(dr + q * 2048) = rb;
  }
}

// ==========================================================================
// gemm2h: fused GEMM2 + h-epilogue, A-reuse version. Grid 256 = (mb, cgp);
// each block loops cg in {2cgp, 2cgp+1}, running the full 128-tile K-loop
// per cg. A2p[mb] (2MB) is re-streamed from L2/L3-warm addresses on the 2nd
// pass -> A HBM traffic ~halved vs R10's 8-way re-read. 1 block/CU exactly.
// Per cg: ocg = c_new@W_o_c (t<64), mt = r_t@W_r_proj (t>=64), dual acc;
// then h = sigmoid(og_pre + ocg + bias_o) * (mt + xr), fp32 write.
// ==========================================================================
__global__ __launch_bounds__(512, 2) void gemm2h_kernel(
    const u16* __restrict__ A2p, const u16* __restrict__ W2q,
    const u16* __restrict__ G1, const float* __restrict__ bias_o,
    float* __restrict__ h_out) {
  constexpr int SLOT = 12288;  // u16: A 8192 + B 4096

  __shared__ u16 lds[3 * SLOT];  // 72 KiB

  int bid = blockIdx.x;          // grid = 256
  int cpx = gridDim.x >> 3;
  bid = (bid & 7) * cpx + (bid >> 3);

  int mb = bid >> 2, cgp = bid & 3;
  int m0 = mb * 256;

  const int tid  = threadIdx.x;
  const int lane = tid & 63;
  const int wid  = tid >> 6;
  const int wr   = wid >> 1;     // 0..3 (64-row band)
  const int wc   = wid & 1;      // 0..1 (64-col band)
  const int hl16 = lane >> 4;
  const int l15  = lane & 15;

  const int dstg = tid * 8;  // u16, < 4096
  const u16* pA = A2p + ((long)(mb * 128)) * 8192 + dstg;

  const int aoff = hl16 * 2048 + (wr * 64 + l15) * 8;  // + m*128
  const int boff = hl16 * 1024 + (wc * 64 + l15) * 8;  // + n*128

#define STAGE2(t, s) do { \
    gload16(pA + (long)(t) * 8192,        &lds[(s) * SLOT + dstg]); \
    gload16(pA + (long)(t) * 8192 + 4096, &lds[(s) * SLOT + dstg + 4096]); \
    gload16(pB + (long)(t) * 4096,        &lds[(s) * SLOT + 8192 + dstg]); } while (0)

#pragma unroll 1
  for (int ci = 0; ci < 2; ++ci) {
    const int cg = cgp * 2 + ci;
    const int c0 = cg * 128;
    const u16* pB = W2q + ((long)(cg * 128)) * 4096 + dstg;

    f32x4_t acc0[4][4], acc1[4][4];
#pragma unroll
    for (int m = 0; m < 4; ++m)
#pragma unroll
      for (int n = 0; n < 4; ++n) {
        acc0[m][n] = (f32x4_t){0.f, 0.f, 0.f, 0.f};
        acc1[m][n] = (f32x4_t){0.f, 0.f, 0.f, 0.f};
      }

    STAGE2(0, 0); STAGE2(1, 1);
    asm volatile("s_waitcnt vmcnt(3)" ::: "memory");
    __builtin_amdgcn_s_barrier();

    int slot = 0, s2 = 2;
    for (int t = 0; t < 128; ++t) {
      const u16* sA = &lds[slot * SLOT];
      const u16* sB = sA + 8192;
      const bool pre = (t + 2 < 128);
      if (pre) STAGE2(t + 2, s2);

      bf16x8_t wv[4], av[4];
#pragma unroll
      for (int n = 0; n < 4; ++n) wv[n] = *(const bf16x8_t*)&sB[boff + n * 128];
#pragma unroll
      for (int m = 0; m < 4; ++m) av[m] = *(const bf16x8_t*)&sA[aoff + m * 128];

      __builtin_amdgcn_s_setprio(1);
      if (t < 64) {
#pragma unroll
        for (int m = 0; m < 4; ++m)
#pragma unroll
          for (int n = 0; n < 4; ++n)
            acc0[m][n] = __builtin_amdgcn_mfma_f32_16x16x32_bf16(wv[n], av[m], acc0[m][n], 0, 0, 0);
      } else {
#pragma unroll
        for (int m = 0; m < 4; ++m)
#pragma unroll
          for (int n = 0; n < 4; ++n)
            acc1[m][n] = __builtin_amdgcn_mfma_f32_16x16x32_bf16(wv[n], av[m], acc1[m][n], 0, 0, 0);
      }
      __builtin_amdgcn_s_setprio(0);

      if (pre) asm volatile("s_waitcnt vmcnt(3)" ::: "memory");
      else     asm volatile("s_waitcnt vmcnt(0)" ::: "memory");
      __builtin_amdgcn_s_barrier();

      slot = (slot == 2) ? 0 : slot + 1;
      s2   = (s2   == 2) ? 0 : s2   + 1;
    }

    // ---- fused h epilogue for this cg ----
#pragma unroll
    for (int m = 0; m < 4; ++m) {
      int row = m0 + wr * 64 + m * 16 + l15;
      const u16* g1r = G1 + (long)row * 8192;
#pragma unroll
      for (int n = 0; n < 4; ++n) {
        int jb = c0 + wc * 64 + n * 16 + 4 * hl16;
        u16x4_t og = *(const u16x4_t*)(g1r + 6144 + jb);
        u16x4_t xr = *(const u16x4_t*)(g1r + 7168 + jb);
        f32x4_t bo = *(const f32x4_t*)(bias_o + jb);
        f32x4_t h;
#pragma unroll
        for (int r = 0; r < 4; ++r) {
          float ogate = sigm_(acc0[m][n][r] + b2f(og[r]) + bo[r]);
          h[r] = ogate * (acc1[m][n][r] + b2f(xr[r]));
        }
        *(f32x4_t*)&h_out[(long)row * 1024 + jb] = h;
      }
    }
  }
#undef STAGE2
}

// ---------- launch ----------
extern "C" void kernel_launch(void* const* d_in, const int* in_sizes, int n_in,
                              void* d_out, int out_size, void* d_ws, size_t ws_size,
                              hipStream_t stream) {
  const float* x_t      = (const float*)d_in[0];
  const float* h_t      = (const float*)d_in[1];
  const float* c_t      = (const float*)d_in[2];
  const float* w_if_x   = (const float*)d_in[3];
  const float* w_if_h   = (const float*)d_in[4];
  const float* w_if_c   = (const float*)d_in[5];
  const float* bias_i   = (const float*)d_in[6];
  const float* bias_f   = (const float*)d_in[7];
  const float* w_c_x    = (const float*)d_in[8];
  const float* w_c_h    = (const float*)d_in[9];
  const float* bias_c   = (const float*)d_in[10];
  const float* w_o_x    = (const float*)d_in[11];
  const float* w_o_h    = (const float*)d_in[12];
  const float* w_o_c    = (const float*)d_in[13];
  const float* bias_o   = (const float*)d_in[14];
  const float* w_r_proj = (const float*)d_in[15];
  const float* w_r_x    = (const float*)d_in[16];

  char* ws = (char*)d_ws;
  // layout:
  //   A1p  [64][160][8192]u16 @ 0        (160 MiB)
  //   W1tp [32][160][8192]u16 @ 160 MiB  ( 80 MiB)
  //   G1   [16384,8192] bf16  @ 240 MiB  (256 MiB)
  //   W2q  [8][128][4096]u16  @ 496 MiB  (  8 MiB)
  //   A2p  [64][128][8192]u16 @ 0        (aliases A1p, dead after GEMM1)
  u16* A1p  = (u16*)(ws);
  u16* W1tp = (u16*)(ws + 167772160L);
  u16* G1   = (u16*)(ws + 251658240L);
  u16* W2q  = (u16*)(ws + 520093696L);
  u16* A2p  = (u16*)(ws);

  float* h_out = (float*)d_out;
  float* c_out = h_out + 16384L * 1024L;

  // --- stage 0: fused packing ---
  pack_act_kernel<<<dim3(64, 160), 256, 0, stream>>>(x_t, h_t, c_t, A1p);
  pack_w1_kernel<<<dim3(32, 160), 256, 0, stream>>>(w_if_x, w_if_h, w_if_c, w_c_x, w_c_h,
                                                    w_o_x, w_o_h, w_r_x, W1tp);
  pack_w2_kernel<<<dim3(8, 128), 128, 0, stream>>>(w_o_c, w_r_proj, W2q);

  // --- stage 1: big fused GEMM -> all pre-activations ---
  gemm1_kernel<<<2048, 512, 0, stream>>>(A1p, W1tp, G1);

  // --- stage 2: elementwise gates -> c_new + packed A2 ---
  pass2_kernel<<<dim3(64, 64), 256, 0, stream>>>(G1, c_t, bias_i, bias_f, bias_c, c_out, A2p);

  // --- stage 3: fused [ocg|mt] GEMM + h epilogue (A-reuse, grid 256) ---
  gemm2h_kernel<<<256, 512, 0, stream>>>(A2p, W2q, G1, bias_o, h_out);
}

// Round 12
// 1471.633 us; speedup vs baseline: 1.0242x; 1.0242x over previous
//
#include <hip/hip_runtime.h>
#include <hip/hip_bf16.h>
#include <math.h>

typedef unsigned short u16;
typedef __bf16 bf16x8_t __attribute__((ext_vector_type(8)));
typedef float  f32x4_t  __attribute__((ext_vector_type(4)));
typedef float  f32x8_t  __attribute__((ext_vector_type(8)));
typedef u16    u16x4_t  __attribute__((ext_vector_type(4)));
typedef u16    u16x8_t  __attribute__((ext_vector_type(8)));

// ---------- helpers ----------
__device__ __forceinline__ u16 f2b(float f) {
  unsigned u = __builtin_bit_cast(unsigned, f);
  u += 0x7fffu + ((u >> 16) & 1u);      // RNE; inputs are finite
  return (u16)(u >> 16);
}
__device__ __forceinline__ float b2f(u16 h) {
  unsigned u = ((unsigned)h) << 16;
  return __builtin_bit_cast(float, u);
}
__device__ __forceinline__ float sigm_(float x) { return 1.0f / (1.0f + __expf(-x)); }
__device__ __forceinline__ float tanh_(float x) { return 1.0f - 2.0f / (__expf(2.0f * x) + 1.0f); }

__device__ __forceinline__ void gload16(const void* g, void* l) {
  __builtin_amdgcn_global_load_lds(
      (__attribute__((address_space(1))) void*)(g),
      (__attribute__((address_space(3))) void*)(l), 16, 0, 0);
}

// ==========================================================================
// Packed panel formats (k-plane = 8 consecutive k as 16B per row):
//  256-row tiles: [p 0..3][row 0..255][8 u16] = 8192 u16 (16 KB)
//  128-row tiles: [p 0..3][row 0..127][8 u16] = 4096 u16 ( 8 KB)
// Staging = contiguous 16B/thread wave loads; LDS image == packed tile ->
// conflict-free ds_read_b128 fragments.
// ==========================================================================

// ---------- fused activation pack: x|h|c -> A1p (KT=160; x 0..63, h 64..95, c 96..159) ----------
__global__ void pack_act_kernel(const float* __restrict__ x, const float* __restrict__ h,
                                const float* __restrict__ c, u16* __restrict__ A1p) {
  int mb = blockIdx.x, kt = blockIdx.y, t = threadIdx.x;
  const float* src; int C, ccol;
  if (kt < 64)      { src = x; C = 2048; ccol = kt * 32; }
  else if (kt < 96) { src = h; C = 1024; ccol = (kt - 64) * 32; }
  else              { src = c; C = 2048; ccol = (kt - 96) * 32; }
  const float* s = src + (long)(mb * 256 + t) * C + ccol;
  u16* d = A1p + ((long)(mb * 160 + kt)) * 8192 + t * 8;
#pragma unroll
  for (int p = 0; p < 4; ++p) {
    f32x8_t v = *(const f32x8_t*)(s + p * 8);
    u16x8_t o;
#pragma unroll
    for (int r = 0; r < 8; ++r) o[r] = f2b(v[r]);
    *(u16x8_t*)(d + p * 2048) = o;
  }
}

// ---------- fused W1 pack (transposed) -> W1tp[32nb][160kt][8192] ----------
__global__ void pack_w1_kernel(const float* __restrict__ w_if_x, const float* __restrict__ w_if_h,
                               const float* __restrict__ w_if_c, const float* __restrict__ w_c_x,
                               const float* __restrict__ w_c_h,  const float* __restrict__ w_o_x,
                               const float* __restrict__ w_o_h,  const float* __restrict__ w_r_x,
                               u16* __restrict__ W1tp) {
  int nb = blockIdx.x, kt = blockIdx.y, t = threadIdx.x;
  int n0g = nb * 256;
  const float* src; int N, nl, kl;
  if (n0g < 4096) {
    N = 4096; nl = n0g;
    if (kt < 64)      { src = w_if_x; kl = kt * 32; }
    else if (kt < 96) { src = w_if_h; kl = (kt - 64) * 32; }
    else              { src = w_if_c; kl = (kt - 96) * 32; }
  } else if (n0g < 6144) {
    N = 2048; nl = n0g - 4096;
    if (kt < 64)      { src = w_c_x; kl = kt * 32; }
    else if (kt < 96) { src = w_c_h; kl = (kt - 64) * 32; }
    else return;
  } else if (n0g < 7168) {
    N = 1024; nl = n0g - 6144;
    if (kt < 64)      { src = w_o_x; kl = kt * 32; }
    else if (kt < 96) { src = w_o_h; kl = (kt - 64) * 32; }
    else return;
  } else {
    N = 1024; nl = n0g - 7168;
    if (kt < 64)      { src = w_r_x; kl = kt * 32; }
    else return;
  }
  int n = nl + t;
  float tmp[32];
#pragma unroll
  for (int kk = 0; kk < 32; ++kk)
    tmp[kk] = src[(long)(kl + kk) * N + n];
  u16* d = W1tp + ((long)(nb * 160 + kt)) * 8192 + t * 8;
#pragma unroll
  for (int p = 0; p < 4; ++p) {
    u16x8_t o;
#pragma unroll
    for (int r = 0; r < 8; ++r) o[r] = f2b(tmp[p * 8 + r]);
    *(u16x8_t*)(d + p * 2048) = o;
  }
}

// ---------- W2 pack -> W2q[8cg][128kt][4096] (128-row tiles) ----------
__global__ void pack_w2_kernel(const float* __restrict__ w_o_c,
                               const float* __restrict__ w_r_proj, u16* __restrict__ W2q) {
  int cg = blockIdx.x, kt = blockIdx.y, t = threadIdx.x;   // block = 128 threads
  const float* src; int kl;
  if (kt < 64) { src = w_o_c;    kl = kt * 32; }
  else         { src = w_r_proj; kl = (kt - 64) * 32; }
  int n = cg * 128 + t;
  float tmp[32];
#pragma unroll
  for (int kk = 0; kk < 32; ++kk)
    tmp[kk] = src[(long)(kl + kk) * 1024 + n];
  u16* d = W2q + ((long)(cg * 128 + kt)) * 4096 + t * 8;
#pragma unroll
  for (int p = 0; p < 4; ++p) {
    u16x8_t o;
#pragma unroll
    for (int r = 0; r < 8; ++r) o[r] = f2b(tmp[p * 8 + r]);
    *(u16x8_t*)(d + p * 1024) = o;
  }
}

// ==========================================================================
// GEMM1: 256x256 bf16, 16x16x32 MFMA, 8 waves (2M x 4N), BK=32.
// NEW: 4-slot LDS ring (128KB), stage t+3 during t, boundary vmcnt(4)
// certifies slots t+1 AND t+2 at each boundary -> mid-tile register
// prefetch of NEXT tile's fragments (bv[4] + av[0..3], 8 of 12 reads)
// executes on the DS pipe while the current MFMA clusters drain.
// Per tile: STAGE(t+3) | read avQ(av4..7) | 16 MFMA quadA (prefetched)
//           | read next-tile frags | 16 MFMA quadB | vmcnt(4) | barrier.
// Hazards: slot t&3 overwritten by STAGE issued during t+1 (post-barrier),
// after its last reads (avQ, lgkm-drained before quadB) -- race-free.
// ==========================================================================
struct FragSet { bf16x8_t bv[4]; bf16x8_t av[4]; };

__global__ __launch_bounds__(512, 2) void gemm1_kernel(
    const u16* __restrict__ A, const u16* __restrict__ Bt, u16* __restrict__ Cout) {
  constexpr int KTF  = 160;
  constexpr int NCOL = 8192;
  constexpr int NBN  = 32;
  constexpr int SLOT = 16384;   // u16 per ring slot (A 8192 + B 8192)

  __shared__ u16 lds[4 * SLOT];  // 128 KiB

  int bid = blockIdx.x;
  int cpx = gridDim.x >> 3;
  bid = (bid & 7) * cpx + (bid >> 3);

  int mb = bid / NBN, nb = bid % NBN;
  int m0 = mb * 256, n0 = nb * 256;

  int NT = (nb < 16) ? 160 : ((nb < 28) ? 96 : 64);   // always even, >= 64

  const int tid  = threadIdx.x;
  const int lane = tid & 63;
  const int wid  = tid >> 6;
  const int wr   = wid >> 2;       // 0..1
  const int wc   = wid & 3;        // 0..3
  const int hl16 = lane >> 4;      // 0..3 (k-plane)
  const int l15  = lane & 15;

  const int dstg = tid * 8;  // u16
  const u16* pA = A  + ((long)(mb * KTF)) * 8192 + dstg;
  const u16* pB = Bt + ((long)(nb * KTF)) * 8192 + dstg;

#define STAGE(t, s) do { \
    gload16(pA + (long)(t) * 8192,        &lds[(s) * SLOT + dstg]); \
    gload16(pA + (long)(t) * 8192 + 4096, &lds[(s) * SLOT + dstg + 4096]); \
    gload16(pB + (long)(t) * 8192,        &lds[(s) * SLOT + 8192 + dstg]); \
    gload16(pB + (long)(t) * 8192 + 4096, &lds[(s) * SLOT + 8192 + dstg + 4096]); } while (0)

  const int aoff = hl16 * 2048 + (wr * 128 + l15) * 8;  // + m*128 (16 rows)
  const int boff = hl16 * 2048 + (wc * 64  + l15) * 8;  // + n*128

  // read prefetch set (bv[4] + av[0..3]) of the tile in ring slot `si`
#define RD_P(S, si) do { \
    const u16* _pb = &lds[(si) * SLOT]; \
    const u16* _pc = _pb + 8192; \
    _Pragma("unroll") \
    for (int n = 0; n < 4; ++n) S.bv[n] = *(const bf16x8_t*)&_pc[boff + n * 128]; \
    _Pragma("unroll") \
    for (int m = 0; m < 4; ++m) S.av[m] = *(const bf16x8_t*)&_pb[aoff + m * 128]; } while (0)

  // one K32 tile: quadA with prefetched frags, mid-tile reads, quadB
#define ITER(TT, P, N) do { \
    const int _t = (TT); \
    const u16* _sb = &lds[(_t & 3) * SLOT]; \
    if (_t + 3 < NT) STAGE(_t + 3, (_t + 3) & 3); \
    bf16x8_t _aq0 = *(const bf16x8_t*)&_sb[aoff + 4 * 128]; \
    bf16x8_t _aq1 = *(const bf16x8_t*)&_sb[aoff + 5 * 128]; \
    bf16x8_t _aq2 = *(const bf16x8_t*)&_sb[aoff + 6 * 128]; \
    bf16x8_t _aq3 = *(const bf16x8_t*)&_sb[aoff + 7 * 128]; \
    __builtin_amdgcn_s_setprio(1); \
    _Pragma("unroll") \
    for (int m = 0; m < 4; ++m) \
      _Pragma("unroll") \
      for (int n = 0; n < 4; ++n) \
        acc[m][n] = __builtin_amdgcn_mfma_f32_16x16x32_bf16(P.bv[n], P.av[m], acc[m][n], 0, 0, 0); \
    __builtin_amdgcn_s_setprio(0); \
    if (_t + 1 < NT) RD_P(N, (_t + 1) & 3); \
    __builtin_amdgcn_s_setprio(1); \
    _Pragma("unroll") \
    for (int n = 0; n < 4; ++n) { \
      acc[4][n] = __builtin_amdgcn_mfma_f32_16x16x32_bf16(P.bv[n], _aq0, acc[4][n], 0, 0, 0); \
      acc[5][n] = __builtin_amdgcn_mfma_f32_16x16x32_bf16(P.bv[n], _aq1, acc[5][n], 0, 0, 0); \
      acc[6][n] = __builtin_amdgcn_mfma_f32_16x16x32_bf16(P.bv[n], _aq2, acc[6][n], 0, 0, 0); \
      acc[7][n] = __builtin_amdgcn_mfma_f32_16x16x32_bf16(P.bv[n], _aq3, acc[7][n], 0, 0, 0); \
    } \
    __builtin_amdgcn_s_setprio(0); \
    if (_t + 3 < NT) asm volatile("s_waitcnt vmcnt(4)" ::: "memory"); \
    else             asm volatile("s_waitcnt vmcnt(0)" ::: "memory"); \
    __builtin_amdgcn_s_barrier(); \
  } while (0)

  f32x4_t acc[8][4];
#pragma unroll
  for (int m = 0; m < 8; ++m)
#pragma unroll
    for (int n = 0; n < 4; ++n) acc[m][n] = (f32x4_t){0.f, 0.f, 0.f, 0.f};

  // prologue: stage tiles 0,1,2 ; certify 0,1 ; prefetch tile-0 frags
  STAGE(0, 0); STAGE(1, 1); STAGE(2, 2);
  asm volatile("s_waitcnt vmcnt(4)" ::: "memory");
  __builtin_amdgcn_s_barrier();

  FragSet FA, FB;
  RD_P(FA, 0);

  for (int t = 0; t < NT; t += 2) {
    ITER(t,     FA, FB);
    ITER(t + 1, FB, FA);
  }
#undef STAGE
#undef RD_P
#undef ITER

  const int rowm = lane & 15;
  const int col4 = (lane >> 4) * 4;
#pragma unroll
  for (int m = 0; m < 8; ++m) {
    long rg = (long)(m0 + wr * 128 + m * 16 + rowm) * NCOL;
#pragma unroll
    for (int n = 0; n < 4; ++n) {
      int cg = n0 + wc * 64 + n * 16 + col4;
      u16x4_t o;
#pragma unroll
      for (int r = 0; r < 4; ++r) o[r] = f2b(acc[m][n][r]);
      *(u16x4_t*)&Cout[rg + cg] = o;
    }
  }
}

// ---------- pass2: gates -> c_new (fp32), A2 packed = [bf16(c_new) | bf16(tanh(c_new))] ----------
__global__ void pass2_kernel(const u16* __restrict__ G1, const float* __restrict__ c_t,
                             const float* __restrict__ bias_i, const float* __restrict__ bias_f,
                             const float* __restrict__ bias_c,
                             float* __restrict__ c_new_out, u16* __restrict__ A2p) {
  int mb = blockIdx.x, jg = blockIdx.y, t = threadIdx.x;
  int b = mb * 256 + t;
  int j0 = jg * 32;
  const u16* row = G1 + (long)b * 8192 + j0;
  const float* cp_p = c_t + (long)b * 2048 + j0;
  float* co_p = c_new_out + (long)b * 2048 + j0;
  u16* dc = A2p + ((long)(mb * 128 + jg)) * 8192 + t * 8;
  u16* dr = dc + (long)64 * 8192;

#pragma unroll
  for (int q = 0; q < 4; ++q) {
    u16x8_t ip = *(const u16x8_t*)(row + q * 8);
    u16x8_t fp = *(const u16x8_t*)(row + 2048 + q * 8);
    u16x8_t gp = *(const u16x8_t*)(row + 4096 + q * 8);
    f32x8_t cp = *(const f32x8_t*)(cp_p + q * 8);
    f32x8_t bi = *(const f32x8_t*)(bias_i + j0 + q * 8);
    f32x8_t bf = *(const f32x8_t*)(bias_f + j0 + q * 8);
    f32x8_t bc = *(const f32x8_t*)(bias_c + j0 + q * 8);
    f32x8_t cn;
    u16x8_t cb, rb;
#pragma unroll
    for (int r = 0; r < 8; ++r) {
      float ig = sigm_(b2f(ip[r]) + bi[r]);
      float fg = sigm_(b2f(fp[r]) + bf[r]);
      float g  = tanh_(b2f(gp[r]) + bc[r]);
      float c  = fg * cp[r] + ig * g;
      cn[r] = c;
      cb[r] = f2b(c);
      rb[r] = f2b(tanh_(c));
    }
    *(f32x8_t*)(co_p + q * 8) = cn;
    *(u16x8_t*)(dc + q * 2048) = cb;
    *(u16x8_t*)(dr + q * 2048) = rb;
  }
}

// ==========================================================================
// gemm2h (R10 version, best measured): fused GEMM2 + h-epilogue, grid 512.
// Block = (mb, cg): 256 rows x 128 cols; dual acc for ocg (kt<64) and
// mt (kt>=64); h = sigmoid(og_pre + ocg + bias_o) * (mt + xr), fp32 write.
// ==========================================================================
__global__ __launch_bounds__(512, 2) void gemm2h_kernel(
    const u16* __restrict__ A2p, const u16* __restrict__ W2q,
    const u16* __restrict__ G1, const float* __restrict__ bias_o,
    float* __restrict__ h_out) {
  constexpr int SLOT = 12288;  // u16: A 8192 + B 4096

  __shared__ u16 lds[3 * SLOT];  // 72 KiB

  int bid = blockIdx.x;          // grid = 512
  int cpx = gridDim.x >> 3;
  bid = (bid & 7) * cpx + (bid >> 3);

  int mb = bid >> 3, cg = bid & 7;
  int m0 = mb * 256, c0 = cg * 128;

  const int tid  = threadIdx.x;
  const int lane = tid & 63;
  const int wid  = tid >> 6;
  const int wr   = wid >> 1;     // 0..3 (64-row band)
  const int wc   = wid & 1;      // 0..1 (64-col band)
  const int hl16 = lane >> 4;
  const int l15  = lane & 15;

  const int dstg = tid * 8;  // u16, < 4096
  const u16* pA = A2p + ((long)(mb * 128)) * 8192 + dstg;
  const u16* pB = W2q + ((long)(cg * 128)) * 4096 + dstg;

#define STAGE2(t, s) do { \
    gload16(pA + (long)(t) * 8192,        &lds[(s) * SLOT + dstg]); \
    gload16(pA + (long)(t) * 8192 + 4096, &lds[(s) * SLOT + dstg + 4096]); \
    gload16(pB + (long)(t) * 4096,        &lds[(s) * SLOT + 8192 + dstg]); } while (0)

  const int aoff = hl16 * 2048 + (wr * 64 + l15) * 8;  // + m*128
  const int boff = hl16 * 1024 + (wc * 64 + l15) * 8;  // + n*128

  f32x4_t acc0[4][4], acc1[4][4];
#pragma unroll
  for (int m = 0; m < 4; ++m)
#pragma unroll
    for (int n = 0; n < 4; ++n) {
      acc0[m][n] = (f32x4_t){0.f, 0.f, 0.f, 0.f};
      acc1[m][n] = (f32x4_t){0.f, 0.f, 0.f, 0.f};
    }

  STAGE2(0, 0); STAGE2(1, 1);
  asm volatile("s_waitcnt vmcnt(3)" ::: "memory");
  __builtin_amdgcn_s_barrier();

  int slot = 0, s2 = 2;
  for (int t = 0; t < 128; ++t) {
    const u16* sA = &lds[slot * SLOT];
    const u16* sB = sA + 8192;
    const bool pre = (t + 2 < 128);
    if (pre) STAGE2(t + 2, s2);

    bf16x8_t wv[4], av[4];
#pragma unroll
    for (int n = 0; n < 4; ++n) wv[n] = *(const bf16x8_t*)&sB[boff + n * 128];
#pragma unroll
    for (int m = 0; m < 4; ++m) av[m] = *(const bf16x8_t*)&sA[aoff + m * 128];

    __builtin_amdgcn_s_setprio(1);
    if (t < 64) {
#pragma unroll
      for (int m = 0; m < 4; ++m)
#pragma unroll
        for (int n = 0; n < 4; ++n)
          acc0[m][n] = __builtin_amdgcn_mfma_f32_16x16x32_bf16(wv[n], av[m], acc0[m][n], 0, 0, 0);
    } else {
#pragma unroll
      for (int m = 0; m < 4; ++m)
#pragma unroll
        for (int n = 0; n < 4; ++n)
          acc1[m][n] = __builtin_amdgcn_mfma_f32_16x16x32_bf16(wv[n], av[m], acc1[m][n], 0, 0, 0);
    }
    __builtin_amdgcn_s_setprio(0);

    if (pre) asm volatile("s_waitcnt vmcnt(3)" ::: "memory");
    else     asm volatile("s_waitcnt vmcnt(0)" ::: "memory");
    __builtin_amdgcn_s_barrier();

    slot = (slot == 2) ? 0 : slot + 1;
    s2   = (s2   == 2) ? 0 : s2   + 1;
  }
#undef STAGE2

  // ---- fused h epilogue ----
#pragma unroll
  for (int m = 0; m < 4; ++m) {
    int row = m0 + wr * 64 + m * 16 + l15;
    const u16* g1r = G1 + (long)row * 8192;
#pragma unroll
    for (int n = 0; n < 4; ++n) {
      int jb = c0 + wc * 64 + n * 16 + 4 * hl16;
      u16x4_t og = *(const u16x4_t*)(g1r + 6144 + jb);
      u16x4_t xr = *(const u16x4_t*)(g1r + 7168 + jb);
      f32x4_t bo = *(const f32x4_t*)(bias_o + jb);
      f32x4_t h;
#pragma unroll
      for (int r = 0; r < 4; ++r) {
        float ogate = sigm_(acc0[m][n][r] + b2f(og[r]) + bo[r]);
        h[r] = ogate * (acc1[m][n][r] + b2f(xr[r]));
      }
      *(f32x4_t*)&h_out[(long)row * 1024 + jb] = h;
    }
  }
}

// ---------- launch ----------
extern "C" void kernel_launch(void* const* d_in, const int* in_sizes, int n_in,
                              void* d_out, int out_size, void* d_ws, size_t ws_size,
                              hipStream_t stream) {
  const float* x_t      = (const float*)d_in[0];
  const float* h_t      = (const float*)d_in[1];
  const float* c_t      = (const float*)d_in[2];
  const float* w_if_x   = (const float*)d_in[3];
  const float* w_if_h   = (const float*)d_in[4];
  const float* w_if_c   = (const float*)d_in[5];
  const float* bias_i   = (const float*)d_in[6];
  const float* bias_f   = (const float*)d_in[7];
  const float* w_c_x    = (const float*)d_in[8];
  const float* w_c_h    = (const float*)d_in[9];
  const float* bias_c   = (const float*)d_in[10];
  const float* w_o_x    = (const float*)d_in[11];
  const float* w_o_h    = (const float*)d_in[12];
  const float* w_o_c    = (const float*)d_in[13];
  const float* bias_o   = (const float*)d_in[14];
  const float* w_r_proj = (const float*)d_in[15];
  const float* w_r_x    = (const float*)d_in[16];

  char* ws = (char*)d_ws;
  u16* A1p  = (u16*)(ws);
  u16* W1tp = (u16*)(ws + 167772160L);
  u16* G1   = (u16*)(ws + 251658240L);
  u16* W2q  = (u16*)(ws + 520093696L);
  u16* A2p  = (u16*)(ws);               // aliases A1p (dead after GEMM1)

  float* h_out = (float*)d_out;
  float* c_out = h_out + 16384L * 1024L;

  // --- stage 0: fused packing ---
  pack_act_kernel<<<dim3(64, 160), 256, 0, stream>>>(x_t, h_t, c_t, A1p);
  pack_w1_kernel<<<dim3(32, 160), 256, 0, stream>>>(w_if_x, w_if_h, w_if_c, w_c_x, w_c_h,
                                                    w_o_x, w_o_h, w_r_x, W1tp);
  pack_w2_kernel<<<dim3(8, 128), 128, 0, stream>>>(w_o_c, w_r_proj, W2q);

  // --- stage 1: big fused GEMM -> all pre-activations ---
  gemm1_kernel<<<2048, 512, 0, stream>>>(A1p, W1tp, G1);

  // --- stage 2: elementwise gates -> c_new + packed A2 ---
  pass2_kernel<<<dim3(64, 64), 256, 0, stream>>>(G1, c_t, bias_i, bias_f, bias_c, c_out, A2p);

  // --- stage 3: fused [ocg|mt] GEMM + h epilogue ---
  gemm2h_kernel<<<512, 512, 0, stream>>>(A2p, W2q, G1, bias_o, h_out);
}

// Round 13
// 1434.639 us; speedup vs baseline: 1.0506x; 1.0258x over previous
//
#include <hip/hip_runtime.h>
#include <hip/hip_bf16.h>
#include <math.h>

typedef unsigned short u16;
typedef __bf16 bf16x8_t __attribute__((ext_vector_type(8)));
typedef float  f32x4_t  __attribute__((ext_vector_type(4)));
typedef float  f32x8_t  __attribute__((ext_vector_type(8)));
typedef u16    u16x4_t  __attribute__((ext_vector_type(4)));
typedef u16    u16x8_t  __attribute__((ext_vector_type(8)));

// ---------- helpers ----------
__device__ __forceinline__ u16 f2b(float f) {
  unsigned u = __builtin_bit_cast(unsigned, f);
  u += 0x7fffu + ((u >> 16) & 1u);      // RNE; inputs are finite
  return (u16)(u >> 16);
}
__device__ __forceinline__ float b2f(u16 h) {
  unsigned u = ((unsigned)h) << 16;
  return __builtin_bit_cast(float, u);
}
__device__ __forceinline__ float sigm_(float x) { return 1.0f / (1.0f + __expf(-x)); }
__device__ __forceinline__ float tanh_(float x) { return 1.0f - 2.0f / (__expf(2.0f * x) + 1.0f); }

__device__ __forceinline__ void gload16(const void* g, void* l) {
  __builtin_amdgcn_global_load_lds(
      (__attribute__((address_space(1))) void*)(g),
      (__attribute__((address_space(3))) void*)(l), 16, 0, 0);
}

// ==========================================================================
// Packed panel formats (k-plane = 8 consecutive k as 16B per row):
//  256-row tiles: [p 0..3][row 0..255][8 u16] = 8192 u16 (16 KB)
//  128-row tiles: [p 0..3][row 0..127][8 u16] = 4096 u16 ( 8 KB)
// Staging = contiguous 16B/thread wave loads; LDS image == packed tile ->
// conflict-free ds_read_b128 fragments.
// ==========================================================================

// ---------- fused activation pack: x|h|c -> A1p (KT=160; x 0..63, h 64..95, c 96..159) ----------
__global__ void pack_act_kernel(const float* __restrict__ x, const float* __restrict__ h,
                                const float* __restrict__ c, u16* __restrict__ A1p) {
  int mb = blockIdx.x, kt = blockIdx.y, t = threadIdx.x;
  const float* src; int C, ccol;
  if (kt < 64)      { src = x; C = 2048; ccol = kt * 32; }
  else if (kt < 96) { src = h; C = 1024; ccol = (kt - 64) * 32; }
  else              { src = c; C = 2048; ccol = (kt - 96) * 32; }
  const float* s = src + (long)(mb * 256 + t) * C + ccol;
  u16* d = A1p + ((long)(mb * 160 + kt)) * 8192 + t * 8;
#pragma unroll
  for (int p = 0; p < 4; ++p) {
    f32x8_t v = *(const f32x8_t*)(s + p * 8);
    u16x8_t o;
#pragma unroll
    for (int r = 0; r < 8; ++r) o[r] = f2b(v[r]);
    *(u16x8_t*)(d + p * 2048) = o;
  }
}

// ---------- fused W1 pack (transposed) -> W1tp[32nb][160kt][8192] ----------
__global__ void pack_w1_kernel(const float* __restrict__ w_if_x, const float* __restrict__ w_if_h,
                               const float* __restrict__ w_if_c, const float* __restrict__ w_c_x,
                               const float* __restrict__ w_c_h,  const float* __restrict__ w_o_x,
                               const float* __restrict__ w_o_h,  const float* __restrict__ w_r_x,
                               u16* __restrict__ W1tp) {
  int nb = blockIdx.x, kt = blockIdx.y, t = threadIdx.x;
  int n0g = nb * 256;
  const float* src; int N, nl, kl;
  if (n0g < 4096) {
    N = 4096; nl = n0g;
    if (kt < 64)      { src = w_if_x; kl = kt * 32; }
    else if (kt < 96) { src = w_if_h; kl = (kt - 64) * 32; }
    else              { src = w_if_c; kl = (kt - 96) * 32; }
  } else if (n0g < 6144) {
    N = 2048; nl = n0g - 4096;
    if (kt < 64)      { src = w_c_x; kl = kt * 32; }
    else if (kt < 96) { src = w_c_h; kl = (kt - 64) * 32; }
    else return;
  } else if (n0g < 7168) {
    N = 1024; nl = n0g - 6144;
    if (kt < 64)      { src = w_o_x; kl = kt * 32; }
    else if (kt < 96) { src = w_o_h; kl = (kt - 64) * 32; }
    else return;
  } else {
    N = 1024; nl = n0g - 7168;
    if (kt < 64)      { src = w_r_x; kl = kt * 32; }
    else return;
  }
  int n = nl + t;
  float tmp[32];
#pragma unroll
  for (int kk = 0; kk < 32; ++kk)
    tmp[kk] = src[(long)(kl + kk) * N + n];
  u16* d = W1tp + ((long)(nb * 160 + kt)) * 8192 + t * 8;
#pragma unroll
  for (int p = 0; p < 4; ++p) {
    u16x8_t o;
#pragma unroll
    for (int r = 0; r < 8; ++r) o[r] = f2b(tmp[p * 8 + r]);
    *(u16x8_t*)(d + p * 2048) = o;
  }
}

// ---------- W2 pack -> W2q[8cg][128kt][4096] (128-row tiles) ----------
__global__ void pack_w2_kernel(const float* __restrict__ w_o_c,
                               const float* __restrict__ w_r_proj, u16* __restrict__ W2q) {
  int cg = blockIdx.x, kt = blockIdx.y, t = threadIdx.x;   // block = 128 threads
  const float* src; int kl;
  if (kt < 64) { src = w_o_c;    kl = kt * 32; }
  else         { src = w_r_proj; kl = (kt - 64) * 32; }
  int n = cg * 128 + t;
  float tmp[32];
#pragma unroll
  for (int kk = 0; kk < 32; ++kk)
    tmp[kk] = src[(long)(kl + kk) * 1024 + n];
  u16* d = W2q + ((long)(cg * 128 + kt)) * 4096 + t * 8;
#pragma unroll
  for (int p = 0; p < 4; ++p) {
    u16x8_t o;
#pragma unroll
    for (int r = 0; r < 8; ++r) o[r] = f2b(tmp[p * 8 + r]);
    *(u16x8_t*)(d + p * 1024) = o;
  }
}

// ==========================================================================
// GEMM1: 256x256 bf16, 16x16x32 MFMA, 8 waves (2M x 4N), BK=32,
// 4-slot LDS ring (128KB), stage t+3 during t, boundary vmcnt(4).
// R13: staging split A-half before quadA / B-half before quadB so VMEM
// issue interleaves with both MFMA clusters (m201 "2 gloads/phase" cadence).
// All 12 frag ds_reads overlap MFMA: avQ under quadA, next-tile set under
// quadB. Hazards unchanged from R12 (slot t&3 overwritten only after its
// last reads are lgkm-drained and a barrier passed).
// ==========================================================================
struct FragSet { bf16x8_t bv[4]; bf16x8_t av[4]; };

__global__ __launch_bounds__(512, 2) void gemm1_kernel(
    const u16* __restrict__ A, const u16* __restrict__ Bt, u16* __restrict__ Cout) {
  constexpr int KTF  = 160;
  constexpr int NCOL = 8192;
  constexpr int NBN  = 32;
  constexpr int SLOT = 16384;   // u16 per ring slot (A 8192 + B 8192)

  __shared__ u16 lds[4 * SLOT];  // 128 KiB

  int bid = blockIdx.x;
  int cpx = gridDim.x >> 3;
  bid = (bid & 7) * cpx + (bid >> 3);

  int mb = bid / NBN, nb = bid % NBN;
  int m0 = mb * 256, n0 = nb * 256;

  int NT = (nb < 16) ? 160 : ((nb < 28) ? 96 : 64);   // always even, >= 64

  const int tid  = threadIdx.x;
  const int lane = tid & 63;
  const int wid  = tid >> 6;
  const int wr   = wid >> 2;       // 0..1
  const int wc   = wid & 3;        // 0..3
  const int hl16 = lane >> 4;      // 0..3 (k-plane)
  const int l15  = lane & 15;

  const int dstg = tid * 8;  // u16
  const u16* pA = A  + ((long)(mb * KTF)) * 8192 + dstg;
  const u16* pB = Bt + ((long)(nb * KTF)) * 8192 + dstg;

#define STAGE_A(t, s) do { \
    gload16(pA + (long)(t) * 8192,        &lds[(s) * SLOT + dstg]); \
    gload16(pA + (long)(t) * 8192 + 4096, &lds[(s) * SLOT + dstg + 4096]); } while (0)
#define STAGE_B(t, s) do { \
    gload16(pB + (long)(t) * 8192,        &lds[(s) * SLOT + 8192 + dstg]); \
    gload16(pB + (long)(t) * 8192 + 4096, &lds[(s) * SLOT + 8192 + dstg + 4096]); } while (0)

  const int aoff = hl16 * 2048 + (wr * 128 + l15) * 8;  // + m*128 (16 rows)
  const int boff = hl16 * 2048 + (wc * 64  + l15) * 8;  // + n*128

  // read prefetch set (bv[4] + av[0..3]) of the tile in ring slot `si`
#define RD_P(S, si) do { \
    const u16* _pb = &lds[(si) * SLOT]; \
    const u16* _pc = _pb + 8192; \
    _Pragma("unroll") \
    for (int n = 0; n < 4; ++n) S.bv[n] = *(const bf16x8_t*)&_pc[boff + n * 128]; \
    _Pragma("unroll") \
    for (int m = 0; m < 4; ++m) S.av[m] = *(const bf16x8_t*)&_pb[aoff + m * 128]; } while (0)

  // one K32 tile: quadA with prefetched frags, spread staging, quadB
#define ITER(TT, P, N) do { \
    const int _t = (TT); \
    const u16* _sb = &lds[(_t & 3) * SLOT]; \
    const bool _p3 = (_t + 3 < NT); \
    if (_p3) STAGE_A(_t + 3, (_t + 3) & 3); \
    bf16x8_t _aq0 = *(const bf16x8_t*)&_sb[aoff + 4 * 128]; \
    bf16x8_t _aq1 = *(const bf16x8_t*)&_sb[aoff + 5 * 128]; \
    bf16x8_t _aq2 = *(const bf16x8_t*)&_sb[aoff + 6 * 128]; \
    bf16x8_t _aq3 = *(const bf16x8_t*)&_sb[aoff + 7 * 128]; \
    __builtin_amdgcn_s_setprio(1); \
    _Pragma("unroll") \
    for (int m = 0; m < 4; ++m) \
      _Pragma("unroll") \
      for (int n = 0; n < 4; ++n) \
        acc[m][n] = __builtin_amdgcn_mfma_f32_16x16x32_bf16(P.bv[n], P.av[m], acc[m][n], 0, 0, 0); \
    __builtin_amdgcn_s_setprio(0); \
    if (_p3) STAGE_B(_t + 3, (_t + 3) & 3); \
    if (_t + 1 < NT) RD_P(N, (_t + 1) & 3); \
    __builtin_amdgcn_s_setprio(1); \
    _Pragma("unroll") \
    for (int n = 0; n < 4; ++n) { \
      acc[4][n] = __builtin_amdgcn_mfma_f32_16x16x32_bf16(P.bv[n], _aq0, acc[4][n], 0, 0, 0); \
      acc[5][n] = __builtin_amdgcn_mfma_f32_16x16x32_bf16(P.bv[n], _aq1, acc[5][n], 0, 0, 0); \
      acc[6][n] = __builtin_amdgcn_mfma_f32_16x16x32_bf16(P.bv[n], _aq2, acc[6][n], 0, 0, 0); \
      acc[7][n] = __builtin_amdgcn_mfma_f32_16x16x32_bf16(P.bv[n], _aq3, acc[7][n], 0, 0, 0); \
    } \
    __builtin_amdgcn_s_setprio(0); \
    if (_p3) asm volatile("s_waitcnt vmcnt(4)" ::: "memory"); \
    else     asm volatile("s_waitcnt vmcnt(0)" ::: "memory"); \
    __builtin_amdgcn_s_barrier(); \
  } while (0)

  f32x4_t acc[8][4];
#pragma unroll
  for (int m = 0; m < 8; ++m)
#pragma unroll
    for (int n = 0; n < 4; ++n) acc[m][n] = (f32x4_t){0.f, 0.f, 0.f, 0.f};

  // prologue: stage tiles 0,1,2 ; certify 0,1 ; prefetch tile-0 frags
  STAGE_A(0, 0); STAGE_B(0, 0);
  STAGE_A(1, 1); STAGE_B(1, 1);
  STAGE_A(2, 2); STAGE_B(2, 2);
  asm volatile("s_waitcnt vmcnt(4)" ::: "memory");
  __builtin_amdgcn_s_barrier();

  FragSet FA, FB;
  RD_P(FA, 0);

  for (int t = 0; t < NT; t += 2) {
    ITER(t,     FA, FB);
    ITER(t + 1, FB, FA);
  }
#undef STAGE_A
#undef STAGE_B
#undef RD_P
#undef ITER

  const int rowm = lane & 15;
  const int col4 = (lane >> 4) * 4;
#pragma unroll
  for (int m = 0; m < 8; ++m) {
    long rg = (long)(m0 + wr * 128 + m * 16 + rowm) * NCOL;
#pragma unroll
    for (int n = 0; n < 4; ++n) {
      int cg = n0 + wc * 64 + n * 16 + col4;
      u16x4_t o;
#pragma unroll
      for (int r = 0; r < 4; ++r) o[r] = f2b(acc[m][n][r]);
      *(u16x4_t*)&Cout[rg + cg] = o;
    }
  }
}

// ---------- pass2: gates -> c_new (fp32), A2 packed = [bf16(c_new) | bf16(tanh(c_new))] ----------
__global__ void pass2_kernel(const u16* __restrict__ G1, const float* __restrict__ c_t,
                             const float* __restrict__ bias_i, const float* __restrict__ bias_f,
                             const float* __restrict__ bias_c,
                             float* __restrict__ c_new_out, u16* __restrict__ A2p) {
  int mb = blockIdx.x, jg = blockIdx.y, t = threadIdx.x;
  int b = mb * 256 + t;
  int j0 = jg * 32;
  const u16* row = G1 + (long)b * 8192 + j0;
  const float* cp_p = c_t + (long)b * 2048 + j0;
  float* co_p = c_new_out + (long)b * 2048 + j0;
  u16* dc = A2p + ((long)(mb * 128 + jg)) * 8192 + t * 8;
  u16* dr = dc + (long)64 * 8192;

#pragma unroll
  for (int q = 0; q < 4; ++q) {
    u16x8_t ip = *(const u16x8_t*)(row + q * 8);
    u16x8_t fp = *(const u16x8_t*)(row + 2048 + q * 8);
    u16x8_t gp = *(const u16x8_t*)(row + 4096 + q * 8);
    f32x8_t cp = *(const f32x8_t*)(cp_p + q * 8);
    f32x8_t bi = *(const f32x8_t*)(bias_i + j0 + q * 8);
    f32x8_t bf = *(const f32x8_t*)(bias_f + j0 + q * 8);
    f32x8_t bc = *(const f32x8_t*)(bias_c + j0 + q * 8);
    f32x8_t cn;
    u16x8_t cb, rb;
#pragma unroll
    for (int r = 0; r < 8; ++r) {
      float ig = sigm_(b2f(ip[r]) + bi[r]);
      float fg = sigm_(b2f(fp[r]) + bf[r]);
      float g  = tanh_(b2f(gp[r]) + bc[r]);
      float c  = fg * cp[r] + ig * g;
      cn[r] = c;
      cb[r] = f2b(c);
      rb[r] = f2b(tanh_(c));
    }
    *(f32x8_t*)(co_p + q * 8) = cn;
    *(u16x8_t*)(dc + q * 2048) = cb;
    *(u16x8_t*)(dr + q * 2048) = rb;
  }
}

// ==========================================================================
// gemm2h: fused GEMM2 + h-epilogue, grid 512. Block = (mb, cg): 256 rows x
// 128 cols; dual acc for ocg (kt<64) and mt (kt>=64);
// h = sigmoid(og_pre + ocg + bias_o) * (mt + xr), fp32 write.
// ==========================================================================
__global__ __launch_bounds__(512, 2) void gemm2h_kernel(
    const u16* __restrict__ A2p, const u16* __restrict__ W2q,
    const u16* __restrict__ G1, const float* __restrict__ bias_o,
    float* __restrict__ h_out) {
  constexpr int SLOT = 12288;  // u16: A 8192 + B 4096

  __shared__ u16 lds[3 * SLOT];  // 72 KiB

  int bid = blockIdx.x;          // grid = 512
  int cpx = gridDim.x >> 3;
  bid = (bid & 7) * cpx + (bid >> 3);

  int mb = bid >> 3, cg = bid & 7;
  int m0 = mb * 256, c0 = cg * 128;

  const int tid  = threadIdx.x;
  const int lane = tid & 63;
  const int wid  = tid >> 6;
  const int wr   = wid >> 1;     // 0..3 (64-row band)
  const int wc   = wid & 1;      // 0..1 (64-col band)
  const int hl16 = lane >> 4;
  const int l15  = lane & 15;

  const int dstg = tid * 8;  // u16, < 4096
  const u16* pA = A2p + ((long)(mb * 128)) * 8192 + dstg;
  const u16* pB = W2q + ((long)(cg * 128)) * 4096 + dstg;

#define STAGE2(t, s) do { \
    gload16(pA + (long)(t) * 8192,        &lds[(s) * SLOT + dstg]); \
    gload16(pA + (long)(t) * 8192 + 4096, &lds[(s) * SLOT + dstg + 4096]); \
    gload16(pB + (long)(t) * 4096,        &lds[(s) * SLOT + 8192 + dstg]); } while (0)

  const int aoff = hl16 * 2048 + (wr * 64 + l15) * 8;  // + m*128
  const int boff = hl16 * 1024 + (wc * 64 + l15) * 8;  // + n*128

  f32x4_t acc0[4][4], acc1[4][4];
#pragma unroll
  for (int m = 0; m < 4; ++m)
#pragma unroll
    for (int n = 0; n < 4; ++n) {
      acc0[m][n] = (f32x4_t){0.f, 0.f, 0.f, 0.f};
      acc1[m][n] = (f32x4_t){0.f, 0.f, 0.f, 0.f};
    }

  STAGE2(0, 0); STAGE2(1, 1);
  asm volatile("s_waitcnt vmcnt(3)" ::: "memory");
  __builtin_amdgcn_s_barrier();

  int slot = 0, s2 = 2;
  for (int t = 0; t < 128; ++t) {
    const u16* sA = &lds[slot * SLOT];
    const u16* sB = sA + 8192;
    const bool pre = (t + 2 < 128);
    if (pre) STAGE2(t + 2, s2);

    bf16x8_t wv[4], av[4];
#pragma unroll
    for (int n = 0; n < 4; ++n) wv[n] = *(const bf16x8_t*)&sB[boff + n * 128];
#pragma unroll
    for (int m = 0; m < 4; ++m) av[m] = *(const bf16x8_t*)&sA[aoff + m * 128];

    __builtin_amdgcn_s_setprio(1);
    if (t < 64) {
#pragma unroll
      for (int m = 0; m < 4; ++m)
#pragma unroll
        for (int n = 0; n < 4; ++n)
          acc0[m][n] = __builtin_amdgcn_mfma_f32_16x16x32_bf16(wv[n], av[m], acc0[m][n], 0, 0, 0);
    } else {
#pragma unroll
      for (int m = 0; m < 4; ++m)
#pragma unroll
        for (int n = 0; n < 4; ++n)
          acc1[m][n] = __builtin_amdgcn_mfma_f32_16x16x32_bf16(wv[n], av[m], acc1[m][n], 0, 0, 0);
    }
    __builtin_amdgcn_s_setprio(0);

    if (pre) asm volatile("s_waitcnt vmcnt(3)" ::: "memory");
    else     asm volatile("s_waitcnt vmcnt(0)" ::: "memory");
    __builtin_amdgcn_s_barrier();

    slot = (slot == 2) ? 0 : slot + 1;
    s2   = (s2   == 2) ? 0 : s2   + 1;
  }
#undef STAGE2

  // ---- fused h epilogue ----
#pragma unroll
  for (int m = 0; m < 4; ++m) {
    int row = m0 + wr * 64 + m * 16 + l15;
    const u16* g1r = G1 + (long)row * 8192;
#pragma unroll
    for (int n = 0; n < 4; ++n) {
      int jb = c0 + wc * 64 + n * 16 + 4 * hl16;
      u16x4_t og = *(const u16x4_t*)(g1r + 6144 + jb);
      u16x4_t xr = *(const u16x4_t*)(g1r + 7168 + jb);
      f32x4_t bo = *(const f32x4_t*)(bias_o + jb);
      f32x4_t h;
#pragma unroll
      for (int r = 0; r < 4; ++r) {
        float ogate = sigm_(acc0[m][n][r] + b2f(og[r]) + bo[r]);
        h[r] = ogate * (acc1[m][n][r] + b2f(xr[r]));
      }
      *(f32x4_t*)&h_out[(long)row * 1024 + jb] = h;
    }
  }
}

// ---------- launch ----------
extern "C" void kernel_launch(void* const* d_in, const int* in_sizes, int n_in,
                              void* d_out, int out_size, void* d_ws, size_t ws_size,
                              hipStream_t stream) {
  const float* x_t      = (const float*)d_in[0];
  const float* h_t      = (const float*)d_in[1];
  const float* c_t      = (const float*)d_in[2];
  const float* w_if_x   = (const float*)d_in[3];
  const float* w_if_h   = (const float*)d_in[4];
  const float* w_if_c   = (const float*)d_in[5];
  const float* bias_i   = (const float*)d_in[6];
  const float* bias_f   = (const float*)d_in[7];
  const float* w_c_x    = (const float*)d_in[8];
  const float* w_c_h    = (const float*)d_in[9];
  const float* bias_c   = (const float*)d_in[10];
  const float* w_o_x    = (const float*)d_in[11];
  const float* w_o_h    = (const float*)d_in[12];
  const float* w_o_c    = (const float*)d_in[13];
  const float* bias_o   = (const float*)d_in[14];
  const float* w_r_proj = (const float*)d_in[15];
  const float* w_r_x    = (const float*)d_in[16];

  char* ws = (char*)d_ws;
  u16* A1p  = (u16*)(ws);
  u16* W1tp = (u16*)(ws + 167772160L);
  u16* G1   = (u16*)(ws + 251658240L);
  u16* W2q  = (u16*)(ws + 520093696L);
  u16* A2p  = (u16*)(ws);               // aliases A1p (dead after GEMM1)

  float* h_out = (float*)d_out;
  float* c_out = h_out + 16384L * 1024L;

  // --- stage 0: fused packing ---
  pack_act_kernel<<<dim3(64, 160), 256, 0, stream>>>(x_t, h_t, c_t, A1p);
  pack_w1_kernel<<<dim3(32, 160), 256, 0, stream>>>(w_if_x, w_if_h, w_if_c, w_c_x, w_c_h,
                                                    w_o_x, w_o_h, w_r_x, W1tp);
  pack_w2_kernel<<<dim3(8, 128), 128, 0, stream>>>(w_o_c, w_r_proj, W2q);

  // --- stage 1: big fused GEMM -> all pre-activations ---
  gemm1_kernel<<<2048, 512, 0, stream>>>(A1p, W1tp, G1);

  // --- stage 2: elementwise gates -> c_new + packed A2 ---
  pass2_kernel<<<dim3(64, 64), 256, 0, stream>>>(G1, c_t, bias_i, bias_f, bias_c, c_out, A2p);

  // --- stage 3: fused [ocg|mt] GEMM + h epilogue ---
  gemm2h_kernel<<<512, 512, 0, stream>>>(A2p, W2q, G1, bias_o, h_out);
}